// Round 7
// baseline (375.550 us; speedup 1.0000x reference)
//
#include <hip/hip_runtime.h>
#include <hip/hip_bf16.h>

// B=512, I=1152, K=8, L=16, O=7; IK=9216, LO=112.
// Single persistent kernel (256 blocks x 1024 threads, 1 block/CU co-resident)
// with software global barriers. Phases:
//   P0: x -> xbf,xT bf16 + wcT0 = bf16(w/1152)
//   per iter: s (MFMA, 96-way K-split partials) | squash (reduce+squash -> vT)
//             | g (MFMA, 4-way B-split, plain-store bij quarters) | wc (softmax+wcT)
// Iter 3 stops after squash (writes out). 2 dispatches total: init_bar + caps_all.

#define NB 512
#define NI 1152
#define NLO 112
#define NIK 9216
#define KSPLIT 96
#define SPART 57344
#define NBLK 256
#define NTHR 1024

typedef __attribute__((ext_vector_type(8))) short bf16x8;
typedef __attribute__((ext_vector_type(4))) float f32x4;

__device__ __forceinline__ ushort f2bf(float f) {
    __hip_bfloat16 h = __float2bfloat16(f);
    return *(ushort*)&h;
}

__global__ void init_bar(int* bar) {
    if (threadIdx.x < 40) bar[threadIdx.x] = 0;
}

// global barrier: per-phase counter bar[p], monotone generation bar[32].
__device__ __forceinline__ void gbar(int p, int* bar) {
    __syncthreads();                       // waits vmcnt(0): block's stores in L2
    if (threadIdx.x == 0) {
        __threadfence();                   // agent release: wb XCD L2
        if (atomicAdd(&bar[p], 1) == NBLK - 1) {
            atomicExch(&bar[32], p + 1);
        } else {
            while (atomicAdd(&bar[32], 0) < p + 1) __builtin_amdgcn_s_sleep(8);
        }
        __threadfence();                   // agent acquire: inv L1 + XCD L2
    }
    __syncthreads();
}

// ---- P0 helper: x fp32 -> xbf[b][ik], xT[ik][b] (bf16), 64x64 tiles ----
__device__ __forceinline__ void conv_phase(const float* __restrict__ x,
                                           ushort* __restrict__ xbf,
                                           ushort* __restrict__ xT,
                                           int bid, int tid) {
    __shared__ ushort ctile[64][68];
    for (int tile = bid; tile < 1152; tile += NBLK) {
        int kg = tile % 144, bg = tile / 144;
        int k0 = kg * 64, b0 = bg * 64;
        __syncthreads();
        {
            int r = tid >> 4, c4 = (tid & 15) * 4;
            float4 f = *(const float4*)&x[(size_t)(b0 + r) * NIK + k0 + c4];
            ushort4 u = { f2bf(f.x), f2bf(f.y), f2bf(f.z), f2bf(f.w) };
            *(ushort4*)&xbf[(size_t)(b0 + r) * NIK + k0 + c4] = u;
            ctile[r][c4] = u.x; ctile[r][c4 + 1] = u.y;
            ctile[r][c4 + 2] = u.z; ctile[r][c4 + 3] = u.w;
        }
        __syncthreads();
        {
            int kr = tid >> 4, c4 = (tid & 15) * 4;
            ushort4 u = { ctile[c4][kr], ctile[c4 + 1][kr],
                          ctile[c4 + 2][kr], ctile[c4 + 3][kr] };
            *(ushort4*)&xT[(size_t)(k0 + kr) * NB + b0 + c4] = u;
        }
    }
}

// ---- wc tile build (+ softmax over i of sum of 4 bij quarters when it>0) ----
__device__ __forceinline__ void wc_build(int it, int ik0, const float* __restrict__ bijp,
                                         const float* __restrict__ w,
                                         ushort* __restrict__ wcT, int tid) {
    __shared__ ushort wtile[NLO][66];
    __shared__ float cs[128];
    __shared__ float red[NTHR];
    __shared__ float m_l[16], inv_l[16];
    if (it) {
        const float* q0 = bijp;
        const float* q1 = bijp + 18432;
        const float* q2 = bijp + 36864;
        const float* q3 = bijp + 55296;
        float mx = -1e30f;
        for (int e = tid; e < 18432; e += NTHR)     // stride%16==0 -> l = tid&15
            mx = fmaxf(mx, q0[e] + q1[e] + q2[e] + q3[e]);
        red[tid] = mx; __syncthreads();
        if (tid < 16) {
            float m = red[tid];
            for (int j = 1; j < 64; ++j) m = fmaxf(m, red[tid + j * 16]);
            m_l[tid] = m;
        }
        __syncthreads();
        float m = m_l[tid & 15];
        float sm = 0.f;
        for (int e = tid; e < 18432; e += NTHR)
            sm += expf(q0[e] + q1[e] + q2[e] + q3[e] - m);
        red[tid] = sm; __syncthreads();
        if (tid < 16) {
            float s2 = 0.f;
            for (int j = 0; j < 64; ++j) s2 += red[tid + j * 16];
            inv_l[tid] = 1.0f / s2;
        }
        __syncthreads();
        if (tid < 128) {
            int e = (ik0 >> 3) * 16 + tid;
            cs[tid] = expf(q0[e] + q1[e] + q2[e] + q3[e] - m_l[tid & 15]) * inv_l[tid & 15];
        }
    } else {
        if (tid < 128) cs[tid] = 1.0f / 1152.0f;
    }
    __syncthreads();
    for (int e = tid; e < 7168; e += NTHR) {
        int ikl = e / NLO, lo = e - ikl * NLO;
        int il = ((ikl >> 3) << 4) + lo / 7;        // i_local*16 + l
        wtile[lo][ikl] = f2bf(cs[il] * w[(size_t)(ik0 + ikl) * NLO + lo]);
    }
    __syncthreads();
    for (int e = tid; e < 7168; e += NTHR) {
        int lo = e >> 6, ikl = e & 63;
        wcT[(size_t)lo * NIK + ik0 + ikl] = wtile[lo][ikl];
    }
}

// ---- s phase: 3072 wave-jobs = 32 M-tiles x 96 K-chunks, 3 MFMA steps ----
__device__ __forceinline__ void s_phase(const ushort* __restrict__ xbf,
                                        const ushort* __restrict__ wcT,
                                        float* __restrict__ part, int bid, int tid) {
    int w16 = tid >> 6;
    if (w16 >= 12) return;
    int j = bid * 12 + w16;          // 0..3071
    int mt = j & 31, kc = j >> 5;
    int b0 = mt * 16, k0 = kc * 96;
    int lane = tid & 63;
    int row = lane & 15, quad = lane >> 4;
    const ushort* ap = xbf + (size_t)(b0 + row) * NIK + k0 + quad * 8;
    const ushort* bp = wcT + (size_t)row * NIK + k0 + quad * 8;
    f32x4 acc[7];
    #pragma unroll
    for (int nt = 0; nt < 7; ++nt) acc[nt] = (f32x4){0.f, 0.f, 0.f, 0.f};
    #pragma unroll
    for (int ks = 0; ks < 3; ++ks) {
        bf16x8 a = *(const bf16x8*)(ap + ks * 32);
        #pragma unroll
        for (int nt = 0; nt < 7; ++nt) {
            bf16x8 bfr = *(const bf16x8*)(bp + (size_t)nt * 16 * NIK + ks * 32);
            acc[nt] = __builtin_amdgcn_mfma_f32_16x16x32_bf16(a, bfr, acc[nt], 0, 0, 0);
        }
    }
    float* pp = part + (size_t)kc * SPART + (size_t)(b0 + quad * 4) * NLO + row;
    #pragma unroll
    for (int nt = 0; nt < 7; ++nt)
        #pragma unroll
        for (int r = 0; r < 4; ++r)
            pp[(size_t)r * NLO + nt * 16] = acc[nt][r];
}

// ---- squash phase: blocks 0..63, 8 batches each; reduce KSPLIT partials ----
__device__ __forceinline__ void squash_phase(const float* __restrict__ part,
                                             ushort* __restrict__ vT,
                                             float* __restrict__ out, int wout,
                                             int bid, int tid) {
    if (bid >= 64) return;
    __shared__ float sh[8][NLO];
    __shared__ float fac[8][16];
    int b0 = bid * 8;
    int bl = tid / NLO, lo = tid - bl * NLO;   // bl<8 for tid<896
    if (tid < 896) {
        const float* pp = part + (size_t)(b0 + bl) * NLO + lo;
        float sv = 0.f;
        #pragma unroll 8
        for (int kc = 0; kc < KSPLIT; ++kc) sv += pp[(size_t)kc * SPART];
        sh[bl][lo] = sv;
    }
    __syncthreads();
    if (tid < 128) {
        int b2 = tid >> 4, l = tid & 15;
        float sq = 0.f;
        #pragma unroll
        for (int o = 0; o < 7; ++o) { float e = sh[b2][l * 7 + o]; sq += e * e; }
        fac[b2][l] = sqrtf(sq) / (1.0f + sq);   // == (sq/(1+sq))/norm
    }
    __syncthreads();
    if (tid < 896) {
        int l = lo / 7, o = lo - l * 7;
        float vv = sh[bl][lo] * fac[bl][l];
        vT[(size_t)(o * 16 + l) * NB + b0 + bl] = f2bf(vv);
        if (wout) out[(size_t)(b0 + bl) * NLO + o * 16 + l] = vv;
    }
}

// ---- g phase: 2304 wave-jobs = 576 ik-tiles x 4 B-quarters; plain-store bij ----
__device__ __forceinline__ void g_phase(const ushort* __restrict__ xT,
                                        const ushort* __restrict__ vT,
                                        const float* __restrict__ w,
                                        float* __restrict__ bijp, int accum,
                                        int bid, int tid) {
    int w16 = tid >> 6;
    if (w16 >= 9) return;
    int j = bid * 9 + w16;           // 0..2303
    int q = j & 3, mtile = j >> 2;
    int m0 = mtile * 16, kb0 = q * 128;
    int lane = tid & 63;
    int row = lane & 15, quad = lane >> 4;
    const ushort* ap = xT + (size_t)(m0 + row) * NB + kb0 + quad * 8;
    const ushort* bp = vT + (size_t)row * NB + kb0 + quad * 8;
    f32x4 acc[7];
    #pragma unroll
    for (int nt = 0; nt < 7; ++nt) acc[nt] = (f32x4){0.f, 0.f, 0.f, 0.f};
    #pragma unroll
    for (int ks = 0; ks < 4; ++ks) {             // 128/32
        bf16x8 a = *(const bf16x8*)(ap + ks * 32);
        #pragma unroll
        for (int nt = 0; nt < 7; ++nt) {
            bf16x8 bfr = *(const bf16x8*)(bp + (size_t)nt * 16 * NB + ks * 32);
            acc[nt] = __builtin_amdgcn_mfma_f32_16x16x32_bf16(a, bfr, acc[nt], 0, 0, 0);
        }
    }
    // lane holds G[ik=m0+quad*4+r][o*16+l], o=nt, l=row
    float S = 0.f;
    #pragma unroll
    for (int r = 0; r < 4; ++r) {
        int ik = m0 + quad * 4 + r;
        const float* wr = w + (size_t)ik * NLO + row * 7;
        float p = 0.f;
        #pragma unroll
        for (int o = 0; o < 7; ++o) p += wr[o] * acc[o][r];
        S += p;
    }
    float Sp = __shfl_down(S, 16);
    if ((quad & 1) == 0) {
        int i = (m0 >> 3) + (quad >> 1);         // wave owns i,i+1 in its quarter
        float val = (S + Sp) * (1.0f / 512.0f);
        float* dst = bijp + (size_t)q * (NI * 16) + i * 16 + row;
        *dst = accum ? (*dst + val) : val;
    }
}

__global__ __launch_bounds__(NTHR, 4) void caps_all(const float* __restrict__ x,
                                                    const float* __restrict__ w,
                                                    float* __restrict__ out,
                                                    int* __restrict__ bar,
                                                    float* __restrict__ bijp,
                                                    float* __restrict__ part,
                                                    ushort* __restrict__ xbf,
                                                    ushort* __restrict__ xT,
                                                    ushort* __restrict__ wcT,
                                                    ushort* __restrict__ vT) {
    int bid = blockIdx.x, tid = threadIdx.x;
    // P0: convert x; last 144 blocks also build iter-0 wcT (= w/1152)
    conv_phase(x, xbf, xT, bid, tid);
    if (bid >= NBLK - 144) wc_build(0, (bid - (NBLK - 144)) * 64, nullptr, w, wcT, tid);
    int p = 0;
    gbar(p++, bar);
    for (int it = 0; it < 3; ++it) {
        s_phase(xbf, wcT, part, bid, tid);
        gbar(p++, bar);
        squash_phase(part, vT, out, it == 2 ? 1 : 0, bid, tid);
        if (it == 2) break;
        gbar(p++, bar);
        g_phase(xT, vT, w, bijp, it, bid, tid);
        gbar(p++, bar);
        if (bid < 144) wc_build(1, bid * 64, bijp, w, wcT, tid);
        gbar(p++, bar);
    }
}

extern "C" void kernel_launch(void* const* d_in, const int* in_sizes, int n_in,
                              void* d_out, int out_size, void* d_ws, size_t ws_size,
                              hipStream_t stream) {
    const float* x = (const float*)d_in[0];   // [512][9216]
    const float* w = (const float*)d_in[1];   // [9216][112]
    float* out = (float*)d_out;               // [512][112]
    float* ws = (float*)d_ws;
    int*    bar    = (int*)ws;                            // 64 slots
    float*  f_bijp = ws + 64;                             // 4*18432
    float*  f_part = f_bijp + 4 * NI * 16;                // 96*57344
    ushort* xbf    = (ushort*)(f_part + (size_t)KSPLIT * SPART);  // 512*9216
    ushort* xT     = xbf + (size_t)NB * NIK;              // 9216*512
    ushort* wcT    = xT + (size_t)NIK * NB;               // 112*9216
    ushort* vT     = wcT + (size_t)NLO * NIK;             // 112*512
    init_bar<<<1, 64, 0, stream>>>(bar);
    caps_all<<<NBLK, NTHR, 0, stream>>>(x, w, out, bar, f_bijp, f_part,
                                        xbf, xT, wcT, vT);
}

// Round 8
// 229.209 us; speedup vs baseline: 1.6385x; 1.6385x over previous
//
#include <hip/hip_runtime.h>
#include <hip/hip_bf16.h>

// B=512, I=1152, K=8, L=16, O=7; IK=9216, LO=112.
// MFMA routing, bf16 inputs / fp32 accumulate, 11 dispatches:
//   prep0: x->xbf,xT (bf16) + wcT0 = bf16(w/1152)           (fused, once)
//   s_gemm: part[kc] = xbf . wcT (MFMA, 48-way K-split, no LDS)   [R5-proven]
//   squash: reduce partials, squash, write vT bf16 (+out fp32 last iter)
//   g_fused: G = xT.vT (MFMA, 2-way B-split halves, plain stores) [R6-proven]
//   smaxwc: softmax(bij0+bij1) fused with wcT build               [R6-proven]
// Iter 3's bij update is dead code -> skipped. No atomics, no memsets.

#define NB 512
#define NI 1152
#define NLO 112
#define NIK 9216
#define KSPLIT 48            // 48 chunks of 192 k (6 MFMA k-steps)  -- R5 value
#define SPART 57344          // 512*112

typedef __attribute__((ext_vector_type(8))) short bf16x8;
typedef __attribute__((ext_vector_type(4))) float f32x4;

__device__ __forceinline__ ushort f2bf(float f) {
    __hip_bfloat16 h = __float2bfloat16(f);
    return *(ushort*)&h;
}

// ---- body: softmax over i of (bij0+bij1) fused with wcT tile build ----
__device__ __forceinline__ void smaxwc_body(const float* __restrict__ bij0,
                                            const float* __restrict__ bij1,
                                            const float* __restrict__ w,
                                            ushort* __restrict__ wcT,
                                            int ik0, int it0flag) {
    __shared__ ushort tile[NLO][66];
    __shared__ float cs[128];        // [i_local*16 + l], 8 i's per block
    __shared__ float red[256];
    __shared__ float m_l[16], inv_l[16];
    int t = threadIdx.x;
    if (!it0flag) {
        // stride 256 == 0 mod 16 -> thread t always sees l = t&15
        float mx = -1e30f;
        for (int e = t; e < NI * 16; e += 256) mx = fmaxf(mx, bij0[e] + bij1[e]);
        red[t] = mx; __syncthreads();
        if (t < 16) {
            float m = red[t];
            #pragma unroll
            for (int j = 1; j < 16; ++j) m = fmaxf(m, red[t + j * 16]);
            m_l[t] = m;
        }
        __syncthreads();
        float m = m_l[t & 15];
        float sm = 0.f;
        for (int e = t; e < NI * 16; e += 256) sm += expf(bij0[e] + bij1[e] - m);
        red[t] = sm; __syncthreads();
        if (t < 16) {
            float s = 0.f;
            #pragma unroll
            for (int j = 0; j < 16; ++j) s += red[t + j * 16];
            inv_l[t] = 1.0f / s;
        }
        __syncthreads();
        if (t < 128) {
            int i = (ik0 >> 3) + (t >> 4), l = t & 15;
            cs[t] = expf(bij0[i * 16 + l] + bij1[i * 16 + l] - m_l[l]) * inv_l[l];
        }
    } else {
        if (t < 128) cs[t] = 1.0f / 1152.0f;
    }
    __syncthreads();
    for (int e = t; e < 7168; e += 256) {
        int ikl = e / NLO, lo = e - ikl * NLO;
        int il = ((ikl >> 3) << 4) + lo / 7;       // i_local*16 + l
        tile[lo][ikl] = f2bf(cs[il] * w[(size_t)(ik0 + ikl) * NLO + lo]);
    }
    __syncthreads();
    for (int e = t; e < 7168; e += 256) {
        int lo = e >> 6, ikl = e & 63;
        wcT[(size_t)lo * NIK + ik0 + ikl] = tile[lo][ikl];
    }
}

// ---- conv_x body: x fp32 -> xbf [b][ik] and xT [ik][b], both bf16 ----
__device__ __forceinline__ void conv_x_body(const float* __restrict__ x,
                                            ushort* __restrict__ xbf,
                                            ushort* __restrict__ xT, int bid) {
    __shared__ ushort tile[64][68];
    int kg = bid % 144, bg = bid / 144;
    int k0 = kg * 64, b0 = bg * 64;
    int t = threadIdx.x;
    for (int e = t; e < 1024; e += 256) {
        int r = e >> 4, c4 = (e & 15) * 4;
        float4 f = *(const float4*)&x[(size_t)(b0 + r) * NIK + k0 + c4];
        ushort4 u = { f2bf(f.x), f2bf(f.y), f2bf(f.z), f2bf(f.w) };
        *(ushort4*)&xbf[(size_t)(b0 + r) * NIK + k0 + c4] = u;
        tile[r][c4] = u.x; tile[r][c4 + 1] = u.y; tile[r][c4 + 2] = u.z; tile[r][c4 + 3] = u.w;
    }
    __syncthreads();
    for (int e = t; e < 1024; e += 256) {
        int kr = e >> 4, c4 = (e & 15) * 4;
        ushort4 u = { tile[c4][kr], tile[c4 + 1][kr], tile[c4 + 2][kr], tile[c4 + 3][kr] };
        *(ushort4*)&xT[(size_t)(k0 + kr) * NB + b0 + c4] = u;
    }
}

// ---- prep0: conv_x (blocks 0..1151) + iter0 wcT = w/1152 (blocks 1152..1295) ----
__global__ __launch_bounds__(256) void prep0(const float* __restrict__ x,
                                             ushort* __restrict__ xbf,
                                             ushort* __restrict__ xT,
                                             const float* __restrict__ w,
                                             ushort* __restrict__ wcT) {
    if (blockIdx.x < 1152) conv_x_body(x, xbf, xT, blockIdx.x);
    else smaxwc_body(nullptr, nullptr, w, wcT, (blockIdx.x - 1152) * 64, 1);
}

// ---- standalone smaxwc for iters 1,2 ----
__global__ __launch_bounds__(256) void smaxwc(const float* __restrict__ bijp,
                                              const float* __restrict__ w,
                                              ushort* __restrict__ wcT) {
    smaxwc_body(bijp, bijp + NI * 16, w, wcT, blockIdx.x * 64, 0);
}

// ---- s_gemm: pure-MFMA, no LDS. wave = 16b M-tile x 7 N-tiles x 192k chunk ----
__global__ __launch_bounds__(256) void s_gemm(const ushort* __restrict__ xbf,
                                              const ushort* __restrict__ wcT,
                                              float* __restrict__ part) {
    int wid = blockIdx.x * 4 + (threadIdx.x >> 6);   // 384 blocks -> 1536 waves
    int lane = threadIdx.x & 63;
    int mt = wid & 31;               // 32 M-tiles of 16 batches
    int kc = wid >> 5;               // 48 K-chunks of 192
    int b0 = mt * 16, k0 = kc * 192;
    int row = lane & 15, quad = lane >> 4;
    const ushort* ap = xbf + (size_t)(b0 + row) * NIK + k0 + quad * 8;
    const ushort* bp = wcT + (size_t)row * NIK + k0 + quad * 8;   // + nt*16*NIK
    f32x4 acc[7];
    #pragma unroll
    for (int nt = 0; nt < 7; ++nt) acc[nt] = (f32x4){0.f, 0.f, 0.f, 0.f};
    #pragma unroll
    for (int ks = 0; ks < 6; ++ks) {                 // 192/32 k-steps
        bf16x8 a = *(const bf16x8*)(ap + ks * 32);
        #pragma unroll
        for (int nt = 0; nt < 7; ++nt) {
            bf16x8 bfr = *(const bf16x8*)(bp + (size_t)nt * 16 * NIK + ks * 32);
            acc[nt] = __builtin_amdgcn_mfma_f32_16x16x32_bf16(a, bfr, acc[nt], 0, 0, 0);
        }
    }
    float* pp = part + (size_t)kc * SPART + (size_t)(b0 + quad * 4) * NLO + row;
    #pragma unroll
    for (int nt = 0; nt < 7; ++nt)
        #pragma unroll
        for (int r = 0; r < 4; ++r)
            pp[(size_t)r * NLO + nt * 16] = acc[nt][r];
}

// ---- fused K-split reduce + squash; writes vT bf16 (and out fp32 on last iter) ----
__global__ void squash_k(const float* __restrict__ part, ushort* __restrict__ vT,
                         float* __restrict__ out, int write_out) {
    int b = blockIdx.x;          // 512 blocks, 128 threads
    int t = threadIdx.x;
    __shared__ float sh[NLO];
    __shared__ float fac[16];
    float sv = 0.f;
    if (t < NLO) {
        const float* p = part + (size_t)b * NLO + t;
        #pragma unroll 8
        for (int kc = 0; kc < KSPLIT; ++kc) sv += p[(size_t)kc * SPART];
        sh[t] = sv;
    }
    __syncthreads();
    if (t < 16) {
        float sq = 0.f;
        #pragma unroll
        for (int o = 0; o < 7; ++o) { float e = sh[t * 7 + o]; sq += e * e; }
        fac[t] = sqrtf(sq) / (1.0f + sq);   // == (sq/(1+sq))/norm
    }
    __syncthreads();
    if (t < NLO) {
        int l = t / 7, o = t - l * 7;
        float vv = sv * fac[l];
        vT[(size_t)(o * 16 + l) * NB + b] = f2bf(vv);
        if (write_out) out[(size_t)b * NLO + o * 16 + l] = vv;
    }
}

// ---- g_fused: MFMA G-tile over half of B (256), in-register w contraction ----
// Exclusive (half,i,l) ownership -> plain stores; it0 store / it>0 accumulate.
__global__ __launch_bounds__(256) void g_fused(const ushort* __restrict__ xT,
                                               const ushort* __restrict__ vT,
                                               const float* __restrict__ w,
                                               float* __restrict__ bijp, int accum) {
    int wid = blockIdx.x * 4 + (threadIdx.x >> 6);   // 288 blocks -> 1152 waves
    int lane = threadIdx.x & 63;
    int half = wid & 1;
    int m0 = (wid >> 1) * 16;                        // ik tile base
    int kb0 = half * 256;
    int row = lane & 15, quad = lane >> 4;
    const ushort* ap = xT + (size_t)(m0 + row) * NB + kb0 + quad * 8;
    const ushort* bp = vT + (size_t)row * NB + kb0 + quad * 8;    // + nt*16*NB
    f32x4 acc[7];
    #pragma unroll
    for (int nt = 0; nt < 7; ++nt) acc[nt] = (f32x4){0.f, 0.f, 0.f, 0.f};
    #pragma unroll
    for (int ks = 0; ks < 8; ++ks) {                 // 256/32
        bf16x8 a = *(const bf16x8*)(ap + ks * 32);
        #pragma unroll
        for (int nt = 0; nt < 7; ++nt) {
            bf16x8 bfr = *(const bf16x8*)(bp + (size_t)nt * 16 * NB + ks * 32);
            acc[nt] = __builtin_amdgcn_mfma_f32_16x16x32_bf16(a, bfr, acc[nt], 0, 0, 0);
        }
    }
    // lane holds G[ik = m0+quad*4+r][o*16+l], o = nt, l = row
    float S = 0.f;
    #pragma unroll
    for (int r = 0; r < 4; ++r) {
        int ik = m0 + quad * 4 + r;
        const float* wr = w + (size_t)ik * NLO + row * 7;
        float p = 0.f;
        #pragma unroll
        for (int o = 0; o < 7; ++o) p += wr[o] * acc[o][r];
        S += p;
    }
    float Sp = __shfl_down(S, 16);                   // partner quad's 4-ik sum
    if ((quad & 1) == 0) {
        int i = (m0 >> 3) + (quad >> 1);             // wave owns i, i+1 within its half
        float val = (S + Sp) * (1.0f / 512.0f);
        float* dst = bijp + (size_t)half * (NI * 16) + i * 16 + row;
        *dst = accum ? (*dst + val) : val;
    }
}

extern "C" void kernel_launch(void* const* d_in, const int* in_sizes, int n_in,
                              void* d_out, int out_size, void* d_ws, size_t ws_size,
                              hipStream_t stream) {
    const float* x = (const float*)d_in[0];   // [512][9216]
    const float* w = (const float*)d_in[1];   // [9216][112]
    float* out = (float*)d_out;               // [512][112]
    float* ws = (float*)d_ws;
    float*  f_bijp = ws;                                  // 2*18432
    float*  f_part = f_bijp + 2 * NI * 16;                // 48*57344
    ushort* xbf    = (ushort*)(f_part + (size_t)KSPLIT * SPART);  // 512*9216
    ushort* xT     = xbf + (size_t)NB * NIK;              // 9216*512
    ushort* wcT    = xT + (size_t)NIK * NB;               // 112*9216
    ushort* vT     = wcT + (size_t)NLO * NIK;             // 112*512
    prep0<<<1296, 256, 0, stream>>>(x, xbf, xT, w, wcT);
    for (int it = 0; it < 3; ++it) {
        if (it > 0) smaxwc<<<144, 256, 0, stream>>>(f_bijp, w, wcT);
        s_gemm<<<384, 256, 0, stream>>>(xbf, wcT, f_part);
        squash_k<<<512, 128, 0, stream>>>(f_part, vT, out, it == 2 ? 1 : 0);
        if (it < 2) g_fused<<<288, 256, 0, stream>>>(xT, vT, w, f_bijp, it);
    }
}

// Round 9
// 201.652 us; speedup vs baseline: 1.8624x; 1.1367x over previous
//
#include <hip/hip_runtime.h>
#include <hip/hip_bf16.h>

// B=512, I=1152, K=8, L=16, O=7; IK=9216, LO=112.
// MFMA routing, bf16 inputs / fp32 accumulate, 14 dispatches:
//   conv_x: x->xbf,xT (bf16)                                   (once)
//   softmax_col: c = softmax_i(bij0+bij1)                      (iters 1,2)
//   conv_wc: wcT[lo][ik] = bf16(c[i,l]*w[ik,lo])  (it0: c=1/1152)
//   s_gemm: part[kc] = xbf . wcT (MFMA, 96-way K-split, no LDS)
//   squash: reduce partials, squash, write vT bf16 (+out fp32 last iter)
//   g_fused: G = xT.vT (MFMA, 2-way B-split halves, plain stores)
// Iter 3's bij update is dead code -> skipped. No atomics, no memsets.

#define NB 512
#define NI 1152
#define NLO 112
#define NIK 9216
#define KSPLIT 96            // 96 chunks of 96 k (3 MFMA k-steps)
#define SPART 57344          // 512*112

typedef __attribute__((ext_vector_type(8))) short bf16x8;
typedef __attribute__((ext_vector_type(4))) float f32x4;

__device__ __forceinline__ ushort f2bf(float f) {
    __hip_bfloat16 h = __float2bfloat16(f);
    return *(ushort*)&h;
}

// ---- conv_x: x fp32 -> xbf [b][ik] and xT [ik][b], both bf16 ----
__global__ __launch_bounds__(256) void conv_x(const float* __restrict__ x,
                                              ushort* __restrict__ xbf,
                                              ushort* __restrict__ xT) {
    __shared__ ushort tile[64][68];
    int kg = blockIdx.x % 144, bg = blockIdx.x / 144;
    int k0 = kg * 64, b0 = bg * 64;
    int t = threadIdx.x;
    for (int e = t; e < 1024; e += 256) {
        int r = e >> 4, c4 = (e & 15) * 4;
        float4 f = *(const float4*)&x[(size_t)(b0 + r) * NIK + k0 + c4];
        ushort4 u = { f2bf(f.x), f2bf(f.y), f2bf(f.z), f2bf(f.w) };
        *(ushort4*)&xbf[(size_t)(b0 + r) * NIK + k0 + c4] = u;
        tile[r][c4] = u.x; tile[r][c4 + 1] = u.y; tile[r][c4 + 2] = u.z; tile[r][c4 + 3] = u.w;
    }
    __syncthreads();
    for (int e = t; e < 1024; e += 256) {
        int kr = e >> 4, c4 = (e & 15) * 4;
        ushort4 u = { tile[c4][kr], tile[c4 + 1][kr], tile[c4 + 2][kr], tile[c4 + 3][kr] };
        *(ushort4*)&xT[(size_t)(k0 + kr) * NB + b0 + c4] = u;
    }
}

// ---- c[i,l] = softmax over i of (bij0+bij1)[i,l] ----
__global__ void softmax_col(const float* __restrict__ bijp, float* __restrict__ c) {
    const float* b0 = bijp;
    const float* b1 = bijp + NI * 16;
    int l = blockIdx.x;          // 16 blocks
    int t = threadIdx.x;         // 256 threads
    __shared__ float red[256];
    float m = -1e30f;
    for (int i = t; i < NI; i += 256) m = fmaxf(m, b0[i * 16 + l] + b1[i * 16 + l]);
    red[t] = m; __syncthreads();
    for (int s = 128; s > 0; s >>= 1) {
        if (t < s) red[t] = fmaxf(red[t], red[t + s]);
        __syncthreads();
    }
    m = red[0]; __syncthreads();
    float sum = 0.f;
    for (int i = t; i < NI; i += 256) sum += expf(b0[i * 16 + l] + b1[i * 16 + l] - m);
    red[t] = sum; __syncthreads();
    for (int s = 128; s > 0; s >>= 1) {
        if (t < s) red[t] += red[t + s];
        __syncthreads();
    }
    float inv = 1.0f / red[0];
    for (int i = t; i < NI; i += 256)
        c[i * 16 + l] = expf(b0[i * 16 + l] + b1[i * 16 + l] - m) * inv;
}

// ---- conv_wc: wcT[lo][ik] = bf16(c[i,l] * w[ik][lo]); it0 -> c = 1/1152 ----
__global__ __launch_bounds__(256) void conv_wc(const float* __restrict__ c,
                                               const float* __restrict__ w,
                                               ushort* __restrict__ wcT, int it0) {
    __shared__ ushort tile[NLO][66];
    __shared__ float cs[128];
    int ik0 = blockIdx.x * 64;        // 144 blocks
    int t = threadIdx.x;
    if (t < 128) cs[t] = it0 ? (1.0f / 1152.0f) : c[(size_t)(ik0 >> 3) * 16 + t];
    __syncthreads();
    for (int e = t; e < 7168; e += 256) {
        int ikl = e / NLO, lo = e - ikl * NLO;
        int il = ((ikl >> 3) << 4) + lo / 7;      // i_local*16 + l
        tile[lo][ikl] = f2bf(cs[il] * w[(size_t)(ik0 + ikl) * NLO + lo]);
    }
    __syncthreads();
    for (int e = t; e < 7168; e += 256) {
        int lo = e >> 6, ikl = e & 63;
        wcT[(size_t)lo * NIK + ik0 + ikl] = tile[lo][ikl];
    }
}

// ---- s_gemm: pure-MFMA, no LDS. wave = 16b M-tile x 7 N-tiles x 96k chunk ----
__global__ __launch_bounds__(256) void s_gemm(const ushort* __restrict__ xbf,
                                              const ushort* __restrict__ wcT,
                                              float* __restrict__ part) {
    int wid = blockIdx.x * 4 + (threadIdx.x >> 6);   // 768 blocks -> 3072 waves
    int lane = threadIdx.x & 63;
    int mt = wid & 31;               // 32 M-tiles of 16 batches
    int kc = wid >> 5;               // 96 K-chunks of 96
    int b0 = mt * 16, k0 = kc * 96;
    int row = lane & 15, quad = lane >> 4;
    const ushort* ap = xbf + (size_t)(b0 + row) * NIK + k0 + quad * 8;
    const ushort* bp = wcT + (size_t)row * NIK + k0 + quad * 8;   // + nt*16*NIK
    f32x4 acc[7];
    #pragma unroll
    for (int nt = 0; nt < 7; ++nt) acc[nt] = (f32x4){0.f, 0.f, 0.f, 0.f};
    #pragma unroll
    for (int ks = 0; ks < 3; ++ks) {                 // 96/32 k-steps
        bf16x8 a = *(const bf16x8*)(ap + ks * 32);
        #pragma unroll
        for (int nt = 0; nt < 7; ++nt) {
            bf16x8 bfr = *(const bf16x8*)(bp + (size_t)nt * 16 * NIK + ks * 32);
            acc[nt] = __builtin_amdgcn_mfma_f32_16x16x32_bf16(a, bfr, acc[nt], 0, 0, 0);
        }
    }
    float* pp = part + (size_t)kc * SPART + (size_t)(b0 + quad * 4) * NLO + row;
    #pragma unroll
    for (int nt = 0; nt < 7; ++nt)
        #pragma unroll
        for (int r = 0; r < 4; ++r)
            pp[(size_t)r * NLO + nt * 16] = acc[nt][r];
}

// ---- fused K-split reduce + squash; writes vT bf16 (and out fp32 on last iter) ----
__global__ void squash_k(const float* __restrict__ part, ushort* __restrict__ vT,
                         float* __restrict__ out, int write_out) {
    int b = blockIdx.x;          // 512 blocks, 128 threads
    int t = threadIdx.x;
    __shared__ float sh[NLO];
    __shared__ float fac[16];
    float sv = 0.f;
    if (t < NLO) {
        const float* p = part + (size_t)b * NLO + t;
        #pragma unroll 8
        for (int kc = 0; kc < KSPLIT; ++kc) sv += p[(size_t)kc * SPART];
        sh[t] = sv;
    }
    __syncthreads();
    if (t < 16) {
        float sq = 0.f;
        #pragma unroll
        for (int o = 0; o < 7; ++o) { float e = sh[t * 7 + o]; sq += e * e; }
        fac[t] = sqrtf(sq) / (1.0f + sq);   // == (sq/(1+sq))/norm
    }
    __syncthreads();
    if (t < NLO) {
        int l = t / 7, o = t - l * 7;
        float vv = sv * fac[l];
        vT[(size_t)(o * 16 + l) * NB + b] = f2bf(vv);
        if (write_out) out[(size_t)b * NLO + o * 16 + l] = vv;
    }
}

// ---- g_fused: MFMA G-tile over half of B (256), in-register w contraction ----
// Exclusive (half,i,l) ownership -> plain stores; it0 store / it>0 accumulate.
__global__ __launch_bounds__(256) void g_fused(const ushort* __restrict__ xT,
                                               const ushort* __restrict__ vT,
                                               const float* __restrict__ w,
                                               float* __restrict__ bijp, int accum) {
    int wid = blockIdx.x * 4 + (threadIdx.x >> 6);   // 288 blocks -> 1152 waves
    int lane = threadIdx.x & 63;
    int half = wid & 1;
    int m0 = (wid >> 1) * 16;                        // ik tile base
    int kb0 = half * 256;
    int row = lane & 15, quad = lane >> 4;
    const ushort* ap = xT + (size_t)(m0 + row) * NB + kb0 + quad * 8;
    const ushort* bp = vT + (size_t)row * NB + kb0 + quad * 8;    // + nt*16*NB
    f32x4 acc[7];
    #pragma unroll
    for (int nt = 0; nt < 7; ++nt) acc[nt] = (f32x4){0.f, 0.f, 0.f, 0.f};
    #pragma unroll
    for (int ks = 0; ks < 8; ++ks) {                 // 256/32
        bf16x8 a = *(const bf16x8*)(ap + ks * 32);
        #pragma unroll
        for (int nt = 0; nt < 7; ++nt) {
            bf16x8 bfr = *(const bf16x8*)(bp + (size_t)nt * 16 * NB + ks * 32);
            acc[nt] = __builtin_amdgcn_mfma_f32_16x16x32_bf16(a, bfr, acc[nt], 0, 0, 0);
        }
    }
    // lane holds G[ik = m0+quad*4+r][o*16+l], o = nt, l = row
    float S = 0.f;
    #pragma unroll
    for (int r = 0; r < 4; ++r) {
        int ik = m0 + quad * 4 + r;
        const float* wr = w + (size_t)ik * NLO + row * 7;
        float p = 0.f;
        #pragma unroll
        for (int o = 0; o < 7; ++o) p += wr[o] * acc[o][r];
        S += p;
    }
    float Sp = __shfl_down(S, 16);                   // partner quad's 4-ik sum
    if ((quad & 1) == 0) {
        int i = (m0 >> 3) + (quad >> 1);             // wave owns i, i+1 within its half
        float val = (S + Sp) * (1.0f / 512.0f);
        float* dst = bijp + (size_t)half * (NI * 16) + i * 16 + row;
        *dst = accum ? (*dst + val) : val;
    }
}

extern "C" void kernel_launch(void* const* d_in, const int* in_sizes, int n_in,
                              void* d_out, int out_size, void* d_ws, size_t ws_size,
                              hipStream_t stream) {
    const float* x = (const float*)d_in[0];   // [512][9216]
    const float* w = (const float*)d_in[1];   // [9216][112]
    float* out = (float*)d_out;               // [512][112]
    float* ws = (float*)d_ws;
    float*  f_bijp = ws;                                  // 2*18432
    float*  f_c    = f_bijp + 2 * NI * 16;                // 18432
    float*  f_part = f_c + 18432;                         // 96*57344
    ushort* xbf    = (ushort*)(f_part + (size_t)KSPLIT * SPART);  // 512*9216
    ushort* xT     = xbf + (size_t)NB * NIK;              // 9216*512
    ushort* wcT    = xT + (size_t)NIK * NB;               // 112*9216
    ushort* vT     = wcT + (size_t)NLO * NIK;             // 112*512
    conv_x<<<1152, 256, 0, stream>>>(x, xbf, xT);
    for (int it = 0; it < 3; ++it) {
        if (it > 0) softmax_col<<<16, 256, 0, stream>>>(f_bijp, f_c);
        conv_wc<<<144, 256, 0, stream>>>(f_c, w, wcT, it == 0 ? 1 : 0);
        s_gemm<<<768, 256, 0, stream>>>(xbf, wcT, f_part);
        squash_k<<<512, 128, 0, stream>>>(f_part, vT, out, it == 2 ? 1 : 0);
        if (it < 2) g_fused<<<288, 256, 0, stream>>>(xT, vT, w, f_bijp, it);
    }
}

// Round 10
// 185.886 us; speedup vs baseline: 2.0203x; 1.0848x over previous
//
#include <hip/hip_runtime.h>
#include <hip/hip_bf16.h>

// B=512, I=1152, K=8, L=16, O=7; IK=9216, LO=112.
// MFMA routing, bf16 inputs / fp32 accumulate, 11 dispatches:
//   prep0: x->xbf,xT (bf16) + wcT0 = bf16(w/1152) + Z init          (once)
//   wc_exp: e[i,l]=exp(bij0+bij1); wcT = bf16(e*w); Z_l += partials (iters 1,2)
//   s_gemm: part[kc] = xbf . wcT (MFMA, 96-way K-split, no LDS)
//   squash: reduce partials, s=s~/Z_l, squash, vT bf16 (+out last iter)
//   g_fused: G = xT.vT (MFMA, 2-way B-split halves, plain stores)
// Softmax is deferred: wcT carries unnormalized exp, squash divides by Z_l.
// (exp without max-sub is safe: |bij| = |mean_b v.u_hat| is O(1).)
// Iter 3's bij update is dead code -> skipped. Only 2*16 atomics/iter (Z).

#define NB 512
#define NI 1152
#define NLO 112
#define NIK 9216
#define KSPLIT 96            // 96 chunks of 96 k (3 MFMA k-steps)
#define SPART 57344          // 512*112

typedef __attribute__((ext_vector_type(8))) short bf16x8;
typedef __attribute__((ext_vector_type(4))) float f32x4;

__device__ __forceinline__ ushort f2bf(float f) {
    __hip_bfloat16 h = __float2bfloat16(f);
    return *(ushort*)&h;
}

// ---- conv_x body: x fp32 -> xbf [b][ik] and xT [ik][b], both bf16 ----
__device__ __forceinline__ void conv_x_body(const float* __restrict__ x,
                                            ushort* __restrict__ xbf,
                                            ushort* __restrict__ xT, int bid) {
    __shared__ ushort tile[64][68];
    int kg = bid % 144, bg = bid / 144;
    int k0 = kg * 64, b0 = bg * 64;
    int t = threadIdx.x;
    for (int e = t; e < 1024; e += 256) {
        int r = e >> 4, c4 = (e & 15) * 4;
        float4 f = *(const float4*)&x[(size_t)(b0 + r) * NIK + k0 + c4];
        ushort4 u = { f2bf(f.x), f2bf(f.y), f2bf(f.z), f2bf(f.w) };
        *(ushort4*)&xbf[(size_t)(b0 + r) * NIK + k0 + c4] = u;
        tile[r][c4] = u.x; tile[r][c4 + 1] = u.y; tile[r][c4 + 2] = u.z; tile[r][c4 + 3] = u.w;
    }
    __syncthreads();
    for (int e = t; e < 1024; e += 256) {
        int kr = e >> 4, c4 = (e & 15) * 4;
        ushort4 u = { tile[c4][kr], tile[c4 + 1][kr], tile[c4 + 2][kr], tile[c4 + 3][kr] };
        *(ushort4*)&xT[(size_t)(k0 + kr) * NB + b0 + c4] = u;
    }
}

// ---- wcT tile build from per-i,l factor cs[128] ----
__device__ __forceinline__ void wc_tile(const float* __restrict__ cs_sh,
                                        const float* __restrict__ w,
                                        ushort* __restrict__ wcT, int ik0) {
    __shared__ ushort tile[NLO][66];
    int t = threadIdx.x;
    for (int e = t; e < 7168; e += 256) {
        int ikl = e / NLO, lo = e - ikl * NLO;
        int il = ((ikl >> 3) << 4) + lo / 7;      // i_local*16 + l
        tile[lo][ikl] = f2bf(cs_sh[il] * w[(size_t)(ik0 + ikl) * NLO + lo]);
    }
    __syncthreads();
    for (int e = t; e < 7168; e += 256) {
        int lo = e >> 6, ikl = e & 63;
        wcT[(size_t)lo * NIK + ik0 + ikl] = tile[lo][ikl];
    }
}

// ---- prep0: conv_x (0..1151) + iter0 wcT = w/1152 (1152..1295) + Z init ----
__global__ __launch_bounds__(256) void prep0(const float* __restrict__ x,
                                             ushort* __restrict__ xbf,
                                             ushort* __restrict__ xT,
                                             const float* __restrict__ w,
                                             ushort* __restrict__ wcT,
                                             float* __restrict__ Z) {
    if (blockIdx.x < 1152) { conv_x_body(x, xbf, xT, blockIdx.x); return; }
    __shared__ float cs[128];
    int t = threadIdx.x;
    if (blockIdx.x == 1152 && t < 48) Z[t] = (t < 16) ? 1.0f : 0.0f;  // Z[it0]=1, Z[it1,2]=0
    if (t < 128) cs[t] = 1.0f / 1152.0f;
    __syncthreads();
    wc_tile(cs, w, wcT, (blockIdx.x - 1152) * 64);
}

// ---- wc_exp (iters 1,2): e = exp(bij0+bij1); Z_l += partial; wcT = bf16(e*w) ----
__global__ __launch_bounds__(256) void wc_exp(const float* __restrict__ bijp,
                                              const float* __restrict__ w,
                                              ushort* __restrict__ wcT,
                                              float* __restrict__ Zit) {
    __shared__ float cs[128];
    int ik0 = blockIdx.x * 64;        // 144 blocks, 8 i's each
    int t = threadIdx.x;
    if (t < 128) {
        int e = (ik0 >> 3) * 16 + t;
        cs[t] = expf(bijp[e] + bijp[e + NI * 16]);
    }
    __syncthreads();
    if (t < 16) {
        float z = 0.f;
        #pragma unroll
        for (int j = 0; j < 8; ++j) z += cs[j * 16 + t];
        atomicAdd(&Zit[t], z);
    }
    wc_tile(cs, w, wcT, ik0);
}

// ---- s_gemm: pure-MFMA, no LDS. wave = 16b M-tile x 7 N-tiles x 96k chunk ----
__global__ __launch_bounds__(256) void s_gemm(const ushort* __restrict__ xbf,
                                              const ushort* __restrict__ wcT,
                                              float* __restrict__ part) {
    int wid = blockIdx.x * 4 + (threadIdx.x >> 6);   // 768 blocks -> 3072 waves
    int lane = threadIdx.x & 63;
    int mt = wid & 31;               // 32 M-tiles of 16 batches
    int kc = wid >> 5;               // 96 K-chunks of 96
    int b0 = mt * 16, k0 = kc * 96;
    int row = lane & 15, quad = lane >> 4;
    const ushort* ap = xbf + (size_t)(b0 + row) * NIK + k0 + quad * 8;
    const ushort* bp = wcT + (size_t)row * NIK + k0 + quad * 8;   // + nt*16*NIK
    f32x4 acc[7];
    #pragma unroll
    for (int nt = 0; nt < 7; ++nt) acc[nt] = (f32x4){0.f, 0.f, 0.f, 0.f};
    #pragma unroll
    for (int ks = 0; ks < 3; ++ks) {                 // 96/32 k-steps
        bf16x8 a = *(const bf16x8*)(ap + ks * 32);
        #pragma unroll
        for (int nt = 0; nt < 7; ++nt) {
            bf16x8 bfr = *(const bf16x8*)(bp + (size_t)nt * 16 * NIK + ks * 32);
            acc[nt] = __builtin_amdgcn_mfma_f32_16x16x32_bf16(a, bfr, acc[nt], 0, 0, 0);
        }
    }
    float* pp = part + (size_t)kc * SPART + (size_t)(b0 + quad * 4) * NLO + row;
    #pragma unroll
    for (int nt = 0; nt < 7; ++nt)
        #pragma unroll
        for (int r = 0; r < 4; ++r)
            pp[(size_t)r * NLO + nt * 16] = acc[nt][r];
}

// ---- K-split reduce + deferred-softmax divide + squash -> vT (+out) ----
__global__ void squash_k(const float* __restrict__ part, ushort* __restrict__ vT,
                         float* __restrict__ out, const float* __restrict__ Zit,
                         int write_out) {
    int b = blockIdx.x;          // 512 blocks, 128 threads
    int t = threadIdx.x;
    __shared__ float sh[NLO];
    __shared__ float fac[16];
    __shared__ float zinv[16];
    if (t >= 112 && t < 128) zinv[t - 112] = 1.0f / Zit[t - 112];
    float sv = 0.f;
    if (t < NLO) {
        const float* p = part + (size_t)b * NLO + t;
        #pragma unroll 8
        for (int kc = 0; kc < KSPLIT; ++kc) sv += p[(size_t)kc * SPART];
    }
    __syncthreads();
    if (t < NLO) { sv *= zinv[t / 7]; sh[t] = sv; }
    __syncthreads();
    if (t < 16) {
        float sq = 0.f;
        #pragma unroll
        for (int o = 0; o < 7; ++o) { float e = sh[t * 7 + o]; sq += e * e; }
        fac[t] = sqrtf(sq) / (1.0f + sq);   // == (sq/(1+sq))/norm
    }
    __syncthreads();
    if (t < NLO) {
        int l = t / 7, o = t - l * 7;
        float vv = sv * fac[l];
        vT[(size_t)(o * 16 + l) * NB + b] = f2bf(vv);
        if (write_out) out[(size_t)b * NLO + o * 16 + l] = vv;
    }
}

// ---- g_fused: MFMA G-tile over half of B (256), in-register w contraction ----
// Exclusive (half,i,l) ownership -> plain stores; it0 store / it>0 accumulate.
__global__ __launch_bounds__(256) void g_fused(const ushort* __restrict__ xT,
                                               const ushort* __restrict__ vT,
                                               const float* __restrict__ w,
                                               float* __restrict__ bijp, int accum) {
    int wid = blockIdx.x * 4 + (threadIdx.x >> 6);   // 288 blocks -> 1152 waves
    int lane = threadIdx.x & 63;
    int half = wid & 1;
    int m0 = (wid >> 1) * 16;                        // ik tile base
    int kb0 = half * 256;
    int row = lane & 15, quad = lane >> 4;
    const ushort* ap = xT + (size_t)(m0 + row) * NB + kb0 + quad * 8;
    const ushort* bp = vT + (size_t)row * NB + kb0 + quad * 8;    // + nt*16*NB
    f32x4 acc[7];
    #pragma unroll
    for (int nt = 0; nt < 7; ++nt) acc[nt] = (f32x4){0.f, 0.f, 0.f, 0.f};
    #pragma unroll
    for (int ks = 0; ks < 8; ++ks) {                 // 256/32
        bf16x8 a = *(const bf16x8*)(ap + ks * 32);
        #pragma unroll
        for (int nt = 0; nt < 7; ++nt) {
            bf16x8 bfr = *(const bf16x8*)(bp + (size_t)nt * 16 * NB + ks * 32);
            acc[nt] = __builtin_amdgcn_mfma_f32_16x16x32_bf16(a, bfr, acc[nt], 0, 0, 0);
        }
    }
    // lane holds G[ik = m0+quad*4+r][o*16+l], o = nt, l = row
    float S = 0.f;
    #pragma unroll
    for (int r = 0; r < 4; ++r) {
        int ik = m0 + quad * 4 + r;
        const float* wr = w + (size_t)ik * NLO + row * 7;
        float p = 0.f;
        #pragma unroll
        for (int o = 0; o < 7; ++o) p += wr[o] * acc[o][r];
        S += p;
    }
    float Sp = __shfl_down(S, 16);                   // partner quad's 4-ik sum
    if ((quad & 1) == 0) {
        int i = (m0 >> 3) + (quad >> 1);             // wave owns i, i+1 within its half
        float val = (S + Sp) * (1.0f / 512.0f);
        float* dst = bijp + (size_t)half * (NI * 16) + i * 16 + row;
        *dst = accum ? (*dst + val) : val;
    }
}

extern "C" void kernel_launch(void* const* d_in, const int* in_sizes, int n_in,
                              void* d_out, int out_size, void* d_ws, size_t ws_size,
                              hipStream_t stream) {
    const float* x = (const float*)d_in[0];   // [512][9216]
    const float* w = (const float*)d_in[1];   // [9216][112]
    float* out = (float*)d_out;               // [512][112]
    float* ws = (float*)d_ws;
    float*  f_bijp = ws;                                  // 2*18432
    float*  f_Z    = f_bijp + 2 * NI * 16;                // 3*16
    float*  f_part = f_Z + 48;                            // 96*57344
    ushort* xbf    = (ushort*)(f_part + (size_t)KSPLIT * SPART);  // 512*9216
    ushort* xT     = xbf + (size_t)NB * NIK;              // 9216*512
    ushort* wcT    = xT + (size_t)NIK * NB;               // 112*9216
    ushort* vT     = wcT + (size_t)NLO * NIK;             // 112*512
    prep0<<<1296, 256, 0, stream>>>(x, xbf, xT, w, wcT, f_Z);
    for (int it = 0; it < 3; ++it) {
        if (it > 0) wc_exp<<<144, 256, 0, stream>>>(f_bijp, w, wcT, f_Z + it * 16);
        s_gemm<<<768, 256, 0, stream>>>(xbf, wcT, f_part);
        squash_k<<<512, 128, 0, stream>>>(f_part, vT, out, f_Z + it * 16,
                                          it == 2 ? 1 : 0);
        if (it < 2) g_fused<<<288, 256, 0, stream>>>(xT, vT, w, f_bijp, it);
    }
}

// Round 11
// 177.401 us; speedup vs baseline: 2.1170x; 1.0478x over previous
//
#include <hip/hip_runtime.h>
#include <hip/hip_bf16.h>

// B=512, I=1152, K=8, L=16, O=7; IK=9216, LO=112.
// MFMA routing, bf16 inputs / fp32 accumulate, 9 dispatches:
//   prep0: x->xbf,xT (bf16) + wcT0 = bf16(w/1152) + Z init          (once)
//   s_gemm: part[kc] = xbf . wcT (MFMA, 96-way K-split, no LDS)
//   squash: reduce partials, s=s~/Z_l, squash, vT bf16 (+out last iter)
//   g_wc:  G = xT.vT (MFMA, 8 waves = 4 ik-tiles x 2 B-halves) -> w-contract
//          -> block-local bij update -> exp -> Z atomics -> wcT tile build
// Softmax deferred: wcT carries unnormalized exp, squash divides by Z_l.
// Iter 3's bij update is dead code -> skipped. Only 16 atomics/block (Z).

#define NB 512
#define NI 1152
#define NLO 112
#define NIK 9216
#define KSPLIT 96            // 96 chunks of 96 k (3 MFMA k-steps)
#define SPART 57344          // 512*112

typedef __attribute__((ext_vector_type(8))) short bf16x8;
typedef __attribute__((ext_vector_type(4))) float f32x4;

__device__ __forceinline__ ushort f2bf(float f) {
    __hip_bfloat16 h = __float2bfloat16(f);
    return *(ushort*)&h;
}

// ---- conv_x body: x fp32 -> xbf [b][ik] and xT [ik][b], both bf16 ----
__device__ __forceinline__ void conv_x_body(const float* __restrict__ x,
                                            ushort* __restrict__ xbf,
                                            ushort* __restrict__ xT, int bid) {
    __shared__ ushort tile[64][68];
    int kg = bid % 144, bg = bid / 144;
    int k0 = kg * 64, b0 = bg * 64;
    int t = threadIdx.x;
    for (int e = t; e < 1024; e += 256) {
        int r = e >> 4, c4 = (e & 15) * 4;
        float4 f = *(const float4*)&x[(size_t)(b0 + r) * NIK + k0 + c4];
        ushort4 u = { f2bf(f.x), f2bf(f.y), f2bf(f.z), f2bf(f.w) };
        *(ushort4*)&xbf[(size_t)(b0 + r) * NIK + k0 + c4] = u;
        tile[r][c4] = u.x; tile[r][c4 + 1] = u.y; tile[r][c4 + 2] = u.z; tile[r][c4 + 3] = u.w;
    }
    __syncthreads();
    for (int e = t; e < 1024; e += 256) {
        int kr = e >> 4, c4 = (e & 15) * 4;
        ushort4 u = { tile[c4][kr], tile[c4 + 1][kr], tile[c4 + 2][kr], tile[c4 + 3][kr] };
        *(ushort4*)&xT[(size_t)(k0 + kr) * NB + b0 + c4] = u;
    }
}

// ---- prep0: conv_x (0..1151) + iter0 wcT = w/1152 (1152..1295) + Z init ----
__global__ __launch_bounds__(256) void prep0(const float* __restrict__ x,
                                             ushort* __restrict__ xbf,
                                             ushort* __restrict__ xT,
                                             const float* __restrict__ w,
                                             ushort* __restrict__ wcT,
                                             float* __restrict__ Z) {
    if (blockIdx.x < 1152) { conv_x_body(x, xbf, xT, blockIdx.x); return; }
    __shared__ ushort tile[NLO][66];
    int t = threadIdx.x;
    int ik0 = (blockIdx.x - 1152) * 64;
    if (blockIdx.x == 1152 && t < 48) Z[t] = (t < 16) ? 1.0f : 0.0f;
    const float cv = 1.0f / 1152.0f;
    for (int e = t; e < 7168; e += 256) {
        int ikl = e / NLO, lo = e - ikl * NLO;
        tile[lo][ikl] = f2bf(cv * w[(size_t)(ik0 + ikl) * NLO + lo]);
    }
    __syncthreads();
    for (int e = t; e < 7168; e += 256) {
        int lo = e >> 6, ikl = e & 63;
        wcT[(size_t)lo * NIK + ik0 + ikl] = tile[lo][ikl];
    }
}

// ---- s_gemm: pure-MFMA, no LDS. wave = 16b M-tile x 7 N-tiles x 96k chunk ----
__global__ __launch_bounds__(256) void s_gemm(const ushort* __restrict__ xbf,
                                              const ushort* __restrict__ wcT,
                                              float* __restrict__ part) {
    int wid = blockIdx.x * 4 + (threadIdx.x >> 6);   // 768 blocks -> 3072 waves
    int lane = threadIdx.x & 63;
    int mt = wid & 31;               // 32 M-tiles of 16 batches
    int kc = wid >> 5;               // 96 K-chunks of 96
    int b0 = mt * 16, k0 = kc * 96;
    int row = lane & 15, quad = lane >> 4;
    const ushort* ap = xbf + (size_t)(b0 + row) * NIK + k0 + quad * 8;
    const ushort* bp = wcT + (size_t)row * NIK + k0 + quad * 8;   // + nt*16*NIK
    f32x4 acc[7];
    #pragma unroll
    for (int nt = 0; nt < 7; ++nt) acc[nt] = (f32x4){0.f, 0.f, 0.f, 0.f};
    #pragma unroll
    for (int ks = 0; ks < 3; ++ks) {                 // 96/32 k-steps
        bf16x8 a = *(const bf16x8*)(ap + ks * 32);
        #pragma unroll
        for (int nt = 0; nt < 7; ++nt) {
            bf16x8 bfr = *(const bf16x8*)(bp + (size_t)nt * 16 * NIK + ks * 32);
            acc[nt] = __builtin_amdgcn_mfma_f32_16x16x32_bf16(a, bfr, acc[nt], 0, 0, 0);
        }
    }
    float* pp = part + (size_t)kc * SPART + (size_t)(b0 + quad * 4) * NLO + row;
    #pragma unroll
    for (int nt = 0; nt < 7; ++nt)
        #pragma unroll
        for (int r = 0; r < 4; ++r)
            pp[(size_t)r * NLO + nt * 16] = acc[nt][r];
}

// ---- K-split reduce + deferred-softmax divide + squash -> vT (+out) ----
__global__ void squash_k(const float* __restrict__ part, ushort* __restrict__ vT,
                         float* __restrict__ out, const float* __restrict__ Zit,
                         int write_out) {
    int b = blockIdx.x;          // 512 blocks, 128 threads
    int t = threadIdx.x;
    __shared__ float sh[NLO];
    __shared__ float fac[16];
    __shared__ float zinv[16];
    if (t >= 112 && t < 128) zinv[t - 112] = 1.0f / Zit[t - 112];
    float sv = 0.f;
    if (t < NLO) {
        const float* p = part + (size_t)b * NLO + t;
        #pragma unroll 8
        for (int kc = 0; kc < KSPLIT; ++kc) sv += p[(size_t)kc * SPART];
    }
    __syncthreads();
    if (t < NLO) { sv *= zinv[t / 7]; sh[t] = sv; }
    __syncthreads();
    if (t < 16) {
        float sq = 0.f;
        #pragma unroll
        for (int o = 0; o < 7; ++o) { float e = sh[t * 7 + o]; sq += e * e; }
        fac[t] = sqrtf(sq) / (1.0f + sq);   // == (sq/(1+sq))/norm
    }
    __syncthreads();
    if (t < NLO) {
        int l = t / 7, o = t - l * 7;
        float vv = sv * fac[l];
        vT[(size_t)(o * 16 + l) * NB + b] = f2bf(vv);
        if (write_out) out[(size_t)b * NLO + o * 16 + l] = vv;
    }
}

// ---- g_wc: fused G-MFMA + w-contraction + bij update + exp + Z + wcT build ----
// 144 blocks x 512 threads (8 waves = 4 ik-tiles x 2 B-halves); block owns
// i = blockIdx.x*8 .. +7 exclusively -> plain bij r/w, no atomics except Z.
__global__ __launch_bounds__(512) void g_wc(const ushort* __restrict__ xT,
                                            const ushort* __restrict__ vT,
                                            const float* __restrict__ w,
                                            float* __restrict__ bij,
                                            ushort* __restrict__ wcT,
                                            float* __restrict__ Zit, int accum) {
    __shared__ float bs[2][8][16];
    __shared__ float cs[128];
    __shared__ ushort tile[NLO][66];
    int t = threadIdx.x;
    int wv = t >> 6;                 // 0..7
    int lane = t & 63;
    int half = wv & 1;
    int mt = wv >> 1;                // 0..3
    int m0 = blockIdx.x * 64 + mt * 16;
    int kb0 = half * 256;
    int row = lane & 15, quad = lane >> 4;
    const ushort* ap = xT + (size_t)(m0 + row) * NB + kb0 + quad * 8;
    const ushort* bp = vT + (size_t)row * NB + kb0 + quad * 8;    // + nt*16*NB
    f32x4 acc[7];
    #pragma unroll
    for (int nt = 0; nt < 7; ++nt) acc[nt] = (f32x4){0.f, 0.f, 0.f, 0.f};
    #pragma unroll
    for (int ks = 0; ks < 8; ++ks) {                 // 256/32
        bf16x8 a = *(const bf16x8*)(ap + ks * 32);
        #pragma unroll
        for (int nt = 0; nt < 7; ++nt) {
            bf16x8 bfr = *(const bf16x8*)(bp + (size_t)nt * 16 * NB + ks * 32);
            acc[nt] = __builtin_amdgcn_mfma_f32_16x16x32_bf16(a, bfr, acc[nt], 0, 0, 0);
        }
    }
    // lane holds G[ik = m0+quad*4+r][o*16+l], o = nt, l = row
    float S = 0.f;
    #pragma unroll
    for (int r = 0; r < 4; ++r) {
        int ik = m0 + quad * 4 + r;
        const float* wr = w + (size_t)ik * NLO + row * 7;
        float p = 0.f;
        #pragma unroll
        for (int o = 0; o < 7; ++o) p += wr[o] * acc[o][r];
        S += p;
    }
    float Sp = __shfl_down(S, 16);                   // partner quad's 4-ik sum
    if ((quad & 1) == 0)
        bs[half][mt * 2 + (quad >> 1)][row] = (S + Sp) * (1.0f / 512.0f);
    __syncthreads();
    if (t < 128) {
        int il = t >> 4, l = t & 15;
        int i = blockIdx.x * 8 + il;
        float val = bs[0][il][l] + bs[1][il][l];
        if (accum) val += bij[i * 16 + l];
        bij[i * 16 + l] = val;
        cs[t] = expf(val);
    }
    __syncthreads();
    if (t < 16) {
        float z = 0.f;
        #pragma unroll
        for (int j = 0; j < 8; ++j) z += cs[j * 16 + t];
        atomicAdd(&Zit[t], z);
    }
    int ik0 = blockIdx.x * 64;
    for (int e = t; e < 7168; e += 512) {
        int ikl = e / NLO, lo = e - ikl * NLO;
        int il = ((ikl >> 3) << 4) + lo / 7;         // i_local*16 + l
        tile[lo][ikl] = f2bf(cs[il] * w[(size_t)(ik0 + ikl) * NLO + lo]);
    }
    __syncthreads();
    for (int e = t; e < 7168; e += 512) {
        int lo = e >> 6, ikl = e & 63;
        wcT[(size_t)lo * NIK + ik0 + ikl] = tile[lo][ikl];
    }
}

extern "C" void kernel_launch(void* const* d_in, const int* in_sizes, int n_in,
                              void* d_out, int out_size, void* d_ws, size_t ws_size,
                              hipStream_t stream) {
    const float* x = (const float*)d_in[0];   // [512][9216]
    const float* w = (const float*)d_in[1];   // [9216][112]
    float* out = (float*)d_out;               // [512][112]
    float* ws = (float*)d_ws;
    float*  f_bij  = ws;                                  // 18432
    float*  f_Z    = f_bij + NI * 16;                     // 3*16
    float*  f_part = f_Z + 48;                            // 96*57344
    ushort* xbf    = (ushort*)(f_part + (size_t)KSPLIT * SPART);  // 512*9216
    ushort* xT     = xbf + (size_t)NB * NIK;              // 9216*512
    ushort* wcT    = xT + (size_t)NIK * NB;               // 112*9216
    ushort* vT     = wcT + (size_t)NLO * NIK;             // 112*512
    prep0<<<1296, 256, 0, stream>>>(x, xbf, xT, w, wcT, f_Z);
    for (int it = 0; it < 3; ++it) {
        s_gemm<<<768, 256, 0, stream>>>(xbf, wcT, f_part);
        squash_k<<<512, 128, 0, stream>>>(f_part, vT, out, f_Z + it * 16,
                                          it == 2 ? 1 : 0);
        if (it < 2)
            g_wc<<<144, 512, 0, stream>>>(xT, vT, w, f_bij, wcT,
                                          f_Z + (it + 1) * 16, it);
    }
}